// Round 6
// baseline (93.948 us; speedup 1.0000x reference)
//
#include <hip/hip_runtime.h>

// ---------------------------------------------------------------------------
// StickyHDPHMMVI emission log-likelihood, f16 MFMA formulation:
// out[bt,k] = c0_k - 0.5 * sum_x A[bt,x] * B[k,x]
//   x-chunks c=0..127: c = h*64+d, slot s (e = h*32+s): A=S0[d][e], B=E_k[d][e]
//   c=128,129: A = mu[t],  B = -2*v_k[t]   (t = (c-128)*32 + s)
//   c=130,131: A = var[t], B = E_k[t,t]
// B lane-ordered: BG[((c*3 + j)*64 + kc*4 + g)*8 + q], k = j*16+kc, s = g*8+q
// A built in registers via v_dot2_f32_f16 from LDS-staged f16 F + mu.
// 2-stage software pipeline on both the B stream (global) and fd/mud (LDS).
// ---------------------------------------------------------------------------

#define BT_TOTAL 32768
#define BT_BLK 32

typedef _Float16 f16;
typedef __attribute__((ext_vector_type(8))) _Float16 f16x8;
typedef __attribute__((ext_vector_type(4))) _Float16 f16x4;
typedef __attribute__((ext_vector_type(2))) _Float16 h2;
typedef __attribute__((ext_vector_type(4))) float f32x4;

#if __has_builtin(__builtin_amdgcn_fdot2)
#define DOT2(a, b, c) __builtin_amdgcn_fdot2((a), (b), (c), false)
#else
#define DOT2(a, b, c) fmaf((float)(a)[0], (float)(b)[0], fmaf((float)(a)[1], (float)(b)[1], (c)))
#endif

__device__ __forceinline__ float digammaf_(float x){
  float r = 0.f;
  while (x < 6.f){ r -= 1.f / x; x += 1.f; }
  float xi = 1.f / x;
  float xi2 = xi * xi;
  return r + logf(x) - 0.5f * xi
         - xi2 * (0.083333333333f - xi2 * (0.0083333333333f - xi2 * 0.0039682539683f));
}

__device__ __forceinline__ float wsum64(float x){
  #pragma unroll
  for (int o = 32; o > 0; o >>= 1) x += __shfl_down(x, o);
  return x;  // valid in lane 0
}

// ---------- kernel A: per-k prep (register GJ, 1 barrier/iter) --------------
__global__ __launch_bounds__(256) void prep_kernel(
    const float* __restrict__ mu_k, const float* __restrict__ Psi,
    const float* __restrict__ nu_a, const float* __restrict__ kap_a,
    f16* __restrict__ BG, float* __restrict__ c0o)
{
  const int k = blockIdx.x;
  const int tid = threadIdx.x;
  if (k >= 33){
    const int kck = k - 32;                 // j=2 rows, kc 1..15 -> zero
    for (int i = tid; i < 4224; i += 256){
      int c = i >> 5, g = (i >> 3) & 3, q = i & 7;
      BG[(size_t)((c * 3 + 2) * 64 + kck * 4 + g) * 8 + q] = (f16)0.f;
    }
    if (tid == 0) c0o[k] = 0.f;
    return;
  }
  const int row = tid & 63;
  const int ch  = tid >> 6;        // column chunk: cols [ch*32, ch*32+32) of 128
  const int c0  = ch << 5;

  __shared__ float pr[2][128];
  __shared__ float fc[2][64];
  __shared__ float diag[64];
  __shared__ float muk[64];
  __shared__ float vpart[2][64];
  __shared__ float Ediag[64];

  float Wr[32];
  if (ch < 2){
    const float* Pg = Psi + (size_t)k * 4096 + (size_t)row * 64 + c0;
    #pragma unroll
    for (int c = 0; c < 32; ++c) Wr[c] = Pg[c];
  } else {
    #pragma unroll
    for (int c = 0; c < 32; ++c) Wr[c] = ((c0 - 64 + c) == row) ? 1.f : 0.f;
  }
  if (tid < 64) muk[tid] = mu_k[k * 64 + tid];
  if (row == 0){
    #pragma unroll
    for (int c = 0; c < 32; ++c) pr[0][c0 + c] = Wr[c];
  }
  if (ch == 0) fc[0][row] = Wr[0];
  __syncthreads();

  for (int jh = 0; jh < 2; ++jh){
    #pragma unroll
    for (int jl = 0; jl < 32; ++jl){
      const int j = jh * 32 + jl;
      const int cur = j & 1, nxt = cur ^ 1;
      float piv = pr[cur][j];
      float f = fc[cur][row] * __builtin_amdgcn_rcpf(piv);
      if (row == j && ch == 0) diag[j] = piv;
      if (row != j){
        #pragma unroll
        for (int c = 0; c < 32; ++c) Wr[c] = fmaf(-f, pr[cur][c0 + c], Wr[c]);
      }
      if (j < 63){
        if (row == j + 1){
          #pragma unroll
          for (int c = 0; c < 32; ++c) pr[nxt][c0 + c] = Wr[c];
        }
        if (jl < 31){ if (ch == jh)     fc[nxt][row] = Wr[jl + 1]; }
        else        { if (ch == jh + 1) fc[nxt][row] = Wr[0]; }
      }
      __syncthreads();
    }
  }

  const float nu = nu_a[k];
  const int j_k = k >> 4, kck = k & 15;

  if (ch >= 2){
    const int h = ch - 2;                   // e-half
    const float dinv = nu / diag[row];
    float vp = 0.f;
    #pragma unroll
    for (int c = 0; c < 32; ++c) vp = fmaf(Wr[c], muk[h * 32 + c], vp);
    vpart[h][row] = vp * dinv;
    const int cBG = h * 64 + row;           // chunk (d=row, e-half h)
    f16* dst = BG + (size_t)(cBG * 192 + j_k * 64 + kck * 4) * 8;
    #pragma unroll
    for (int v4 = 0; v4 < 4; ++v4){
      f16x8 ab;
      #pragma unroll
      for (int q = 0; q < 8; ++q){
        float val = Wr[v4 * 8 + q] * dinv;
        ab[q] = (f16)val;
        if ((h * 32 + v4 * 8 + q) == row) Ediag[row] = val;
      }
      *(f16x8*)(dst + v4 * 8) = ab;
    }
  }
  __syncthreads();

  if (tid < 64){
    const int t = tid;
    float v = vpart[0][t] + vpart[1][t];
    const int g = (t >> 3) & 3, q = t & 7;
    const int cA = 128 + (t >> 5);
    const int cB = 130 + (t >> 5);
    BG[(size_t)((cA * 3 + j_k) * 64 + kck * 4 + g) * 8 + q] = (f16)(-2.f * v);
    BG[(size_t)((cB * 3 + j_k) * 64 + kck * 4 + g) * 8 + q] = (f16)(Ediag[t]);
    float c2 = wsum64(v * muk[t]);
    float dg = wsum64(digammaf_((nu - (float)t) * 0.5f));
    float ld = wsum64(logf(diag[t]));
    if (t == 0){
      const float LN2   = 0.69314718055994531f;
      const float LN2PI = 1.83787706640934548f;
      float Elogdet = dg + 64.f * LN2 - ld;
      float cst = 0.5f * (Elogdet - 64.f * LN2PI);
      c0o[k] = cst - 0.5f * c2 - 32.f / kap_a[k];
    }
  }
}

// ---------------- kernel B: main (f16 MFMA, 2-stage pipeline) ---------------
#define BUILD_AF(AF, FD, MUD)                                              \
  {                                                                        \
    h2 fp_[4];                                                             \
    _Pragma("unroll")                                                      \
    for (int r_ = 0; r_ < 4; ++r_){                                        \
      h2 p_ = { (FD)[2 * r_], (FD)[2 * r_ + 1] }; fp_[r_] = p_;            \
    }                                                                      \
    float s_[8];                                                           \
    _Pragma("unroll")                                                      \
    for (int q_ = 0; q_ < 8; ++q_){                                        \
      float a_ = (MUD) * mue[q_];                                          \
      _Pragma("unroll")                                                    \
      for (int r_ = 0; r_ < 4; ++r_) a_ = DOT2(fp_[r_], Fp[q_][r_], a_);   \
      s_[q_] = a_;                                                         \
    }                                                                      \
    _Pragma("unroll")                                                      \
    for (int q_ = 0; q_ < 8; ++q_) (AF)[q_] = (f16)s_[q_];                 \
  }

__global__ __launch_bounds__(256, 4) void main_kernel(
    const float* __restrict__ mu_t, const float* __restrict__ var_t,
    const float* __restrict__ F_t, const unsigned char* __restrict__ maskb,
    const f16* __restrict__ BG, const float* __restrict__ c0o,
    float* __restrict__ out)
{
  __shared__ __align__(16) f16 sG[BT_BLK][64][8];  // F[d][r], d^(bt&7)  32 KB
  __shared__ __align__(16) f16 sMu[BT_BLK][64];    // block-8 d-swizzle   4 KB

  const int tid = threadIdx.x;
  const int l = tid & 63;
  const int w = tid >> 6;
  const int g = l >> 4;
  const int kc = l & 15;
  const int xh = w >> 1;                 // x-half this wave computes
  const int bt0 = blockIdx.x * BT_BLK;
  const int btl = (w & 1) * 16 + kc;     // this lane's local A row
  const int btSw = btl & 7;

  const bool byteMask =
      __any((maskb[4 * l + 1] | maskb[4 * l + 2] | maskb[4 * l + 3]) != 0);

  // ---- stage F / mu into LDS (coalesced, f32->f16) ----
  {
    const float4* fg = (const float4*)(F_t + (size_t)bt0 * 512);
    #pragma unroll
    for (int ii = 0; ii < 16; ++ii){
      int i = tid + ii * 256;
      float4 f = fg[i];
      int bt = i >> 7, rem = i & 127, d = rem >> 1, rb = (rem & 1) << 2;
      int dsw = d ^ (bt & 7);
      f16x4 ff = { (f16)f.x, (f16)f.y, (f16)f.z, (f16)f.w };
      *(f16x4*)&sG[bt][dsw][rb] = ff;
    }
    const float4* mg = (const float4*)(mu_t + (size_t)bt0 * 64);
    #pragma unroll
    for (int ii = 0; ii < 2; ++ii){
      int i = tid + ii * 256;
      float4 m4 = mg[i];
      int bt = i >> 4, d0 = (i & 15) << 2;
      int dsw = (((d0 >> 3) ^ (bt & 7)) << 3) | (d0 & 7);
      f16x4 mm = { (f16)m4.x, (f16)m4.y, (f16)m4.z, (f16)m4.w };
      *(f16x4*)&sMu[bt][dsw] = mm;
    }
  }
  __syncthreads();

  // ---- per-lane register cache: 8 e-columns of F (f16 pairs), mu[e] ----
  const int e0 = xh * 32 + g * 8;
  h2 Fp[8][4];
  float mue[8];
  {
    f16x8 mrow = *(const f16x8*)&sMu[btl][((e0 >> 3) ^ btSw) << 3];
    #pragma unroll
    for (int q = 0; q < 8; ++q){
      f16x8 fv = *(const f16x8*)&sG[btl][(e0 + q) ^ btSw][0];
      #pragma unroll
      for (int r = 0; r < 4; ++r){ h2 p = { fv[2 * r], fv[2 * r + 1] }; Fp[q][r] = p; }
      mue[q] = (float)mrow[q];
    }
  }

  f32x4 acc0 = {0.f,0.f,0.f,0.f}, acc1 = {0.f,0.f,0.f,0.f}, acc2 = {0.f,0.f,0.f,0.f};

  const f16* bp = BG + (size_t)(xh * 64 * 192 + kc * 4 + g) * 8;

  // 2-stage pipeline registers
  f16x8 a0 = *(const f16x8*)(bp);
  f16x8 a1 = *(const f16x8*)(bp + 512);
  f16x8 a2 = *(const f16x8*)(bp + 1024);
  f16x8 c0v = *(const f16x8*)(bp + 1536);
  f16x8 c1v = *(const f16x8*)(bp + 1536 + 512);
  f16x8 c2v = *(const f16x8*)(bp + 1536 + 1024);
  bp += 3072;

  f16x8 fdA = *(const f16x8*)&sG[btl][0 ^ btSw][0];
  f16x8 fdB = *(const f16x8*)&sG[btl][1 ^ btSw][0];
  float mudA = (float)sMu[btl][(((0 >> 3) ^ btSw) << 3) | 0];
  float mudB = (float)sMu[btl][(((1 >> 3) ^ btSw) << 3) | 1];

  for (int d = 0; d < 64; d += 2){
    // ---- even d: consume stage A, refill with chunk d+2 ----
    {
      f16x8 af;
      BUILD_AF(af, fdA, mudA);
      acc0 = __builtin_amdgcn_mfma_f32_16x16x32_f16(af, a0, acc0, 0, 0, 0);
      acc1 = __builtin_amdgcn_mfma_f32_16x16x32_f16(af, a1, acc1, 0, 0, 0);
      acc2 = __builtin_amdgcn_mfma_f32_16x16x32_f16(af, a2, acc2, 0, 0, 0);
      a0 = *(const f16x8*)(bp);
      a1 = *(const f16x8*)(bp + 512);
      a2 = *(const f16x8*)(bp + 1024);
      const int dn = (d + 2) & 63;
      fdA = *(const f16x8*)&sG[btl][dn ^ btSw][0];
      mudA = (float)sMu[btl][(((dn >> 3) ^ btSw) << 3) | (dn & 7)];
    }
    // ---- odd d: consume stage B, refill with chunk d+3 ----
    {
      f16x8 af;
      BUILD_AF(af, fdB, mudB);
      acc0 = __builtin_amdgcn_mfma_f32_16x16x32_f16(af, c0v, acc0, 0, 0, 0);
      acc1 = __builtin_amdgcn_mfma_f32_16x16x32_f16(af, c1v, acc1, 0, 0, 0);
      acc2 = __builtin_amdgcn_mfma_f32_16x16x32_f16(af, c2v, acc2, 0, 0, 0);
      c0v = *(const f16x8*)(bp + 1536);
      c1v = *(const f16x8*)(bp + 1536 + 512);
      c2v = *(const f16x8*)(bp + 1536 + 1024);
      const int dn = (d + 3) & 63;
      fdB = *(const f16x8*)&sG[btl][dn ^ btSw][0];
      mudB = (float)sMu[btl][(((dn >> 3) ^ btSw) << 3) | (dn & 7)];
    }
    bp += 3072;
  }

  // ---- ext chunks: xh=0 -> {128,129} A=mu (LDS);  xh=1 -> {130,131} A=var (global) ----
  #pragma unroll
  for (int m = 0; m < 2; ++m){
    int c = 128 + xh * 2 + m;
    f16x8 af;
    if (xh == 0){
      af = *(const f16x8*)&sMu[btl][((m * 4 + g) ^ btSw) << 3];
    } else {
      const float* vr = var_t + (size_t)(bt0 + btl) * 64 + m * 32 + g * 8;
      f32x4 va = *(const f32x4*)(vr);
      f32x4 vb = *(const f32x4*)(vr + 4);
      #pragma unroll
      for (int r = 0; r < 4; ++r){ af[r] = (f16)va[r]; af[4 + r] = (f16)vb[r]; }
    }
    const f16* bpe = BG + (size_t)(c * 192 + kc * 4 + g) * 8;
    f16x8 b0 = *(const f16x8*)(bpe);
    f16x8 b1 = *(const f16x8*)(bpe + 512);
    f16x8 b2 = *(const f16x8*)(bpe + 1024);
    acc0 = __builtin_amdgcn_mfma_f32_16x16x32_f16(af, b0, acc0, 0, 0, 0);
    acc1 = __builtin_amdgcn_mfma_f32_16x16x32_f16(af, b1, acc1, 0, 0, 0);
    acc2 = __builtin_amdgcn_mfma_f32_16x16x32_f16(af, b2, acc2, 0, 0, 0);
  }

  // ---- cross-wave x reduce (sRed aliased into sG after barrier) ----
  __syncthreads();                         // all waves done reading sG/sMu
  float* sRedF = (float*)sG;               // [2][64][13]
  if (xh == 1){
    const int bofs = ((w - 2) * 64 + l) * 13;
    #pragma unroll
    for (int r = 0; r < 4; ++r){
      sRedF[bofs + r]     = acc0[r];
      sRedF[bofs + 4 + r] = acc1[r];
      sRedF[bofs + 8 + r] = acc2[r];
    }
  }
  __syncthreads();
  if (xh == 0){
    const int bofs = (w * 64 + l) * 13;
    #pragma unroll
    for (int r = 0; r < 4; ++r){
      acc0[r] += sRedF[bofs + r];
      acc1[r] += sRedF[bofs + 4 + r];
      acc2[r] += sRedF[bofs + 8 + r];
    }
    float c0a = c0o[kc];
    float c0b = c0o[16 + kc];
    float c0c = c0o[32];
    #pragma unroll
    for (int reg = 0; reg < 4; ++reg){
      int obt = bt0 + (w & 1) * 16 + g * 4 + reg;
      bool mk = byteMask ? (maskb[obt] != 0) : (maskb[(size_t)4 * obt] != 0);
      float* op = out + (size_t)obt * 33;
      op[kc]      = mk ? fmaf(-0.5f, acc0[reg], c0a) : 0.f;
      op[16 + kc] = mk ? fmaf(-0.5f, acc1[reg], c0b) : 0.f;
      if (kc == 0) op[32] = mk ? fmaf(-0.5f, acc2[reg], c0c) : 0.f;
    }
  }
}

// --------------------------- launch -----------------------------------------
extern "C" void kernel_launch(void* const* d_in, const int* in_sizes, int n_in,
                              void* d_out, int out_size, void* d_ws, size_t ws_size,
                              hipStream_t stream)
{
  const float* mu_t  = (const float*)d_in[0];
  const float* var_t = (const float*)d_in[1];
  const float* F_t   = (const float*)d_in[2];
  const float* mu_k  = (const float*)d_in[3];
  const float* Psi   = (const float*)d_in[4];
  const float* nu    = (const float*)d_in[5];
  const float* kap   = (const float*)d_in[6];
  const unsigned char* mask = (const unsigned char*)d_in[7];

  f16*   BG  = (f16*)d_ws;                      // 132*3*64*8 f16 = 405504 B
  float* c0o = (float*)((char*)d_ws + (size_t)132 * 3 * 64 * 8 * 2);
  float* outp = (float*)d_out;

  hipLaunchKernelGGL(prep_kernel, dim3(48), dim3(256), 0, stream,
                     mu_k, Psi, nu, kap, BG, c0o);
  hipLaunchKernelGGL(main_kernel, dim3(BT_TOTAL / BT_BLK), dim3(256), 0, stream,
                     mu_t, var_t, F_t, mask, BG, c0o, outp);
}